// Round 16
// baseline (286.438 us; speedup 1.0000x reference)
//
#include <hip/hip_runtime.h>
#include <hip/hip_bf16.h>
#include <math.h>

#define N_NODES 80000
#define N_EDGES 1280000
#define NCB 64
#define CB_DIV 1250                 // coarse bucket = dst / 1250 -> 0..63
#define CB_CAP 21000                // mean 20000, +7 sigma
#define NFB 1250                    // fine bucket = dst >> 6 (64 nodes each)
#define FB_CAP 1280                 // mean 1024, +8 sigma
#define EPB 1280                    // edges per k_part block (grid 1000)

typedef __hip_bfloat16 bf16;
typedef __attribute__((ext_vector_type(8))) short bf16x8;   // MFMA A/B frag (4 VGPR)
typedef __attribute__((ext_vector_type(4))) float f32x4;    // MFMA C/D frag

__device__ __forceinline__ float leaky(float x) { return x >= 0.f ? x : 0.01f * x; }

// readlane for float: MUST bit-cast (the builtin is (int,int); passing float
// value-converts and destroys the data — R21's correctness bug).
__device__ __forceinline__ float readlane_f(float v, int l) {
    return __int_as_float(__builtin_amdgcn_readlane(__float_as_int(v), l));
}

__device__ __forceinline__ short bf16bits(float x) {
    bf16 b = __float2bfloat16(x);
    return *(short*)&b;
}

union U4 { uint4 v; bf16 h[8]; };

// ---------------- setup kernels ----------------

// merged zero + weight-pack (one launch). Weights packed in MFMA B-FRAGMENT
// order — frag f = (ct*2+ks)*64+lane holds B[k][c] for
// k = ks*32+(lane>>4)*8+j, c = ct*16+(lane&15).
// pkw[0..511] = lw0T frags; pkw[512..1023] = w1 frags; pkw[1024..1535] = lw1T frags
// NOTE: pkw overlays y3 (disjoint liveness: pkw dead before k_agg3 writes y3)
__global__ void k_init(float* bnsums, float* bnrep, int* ctails, int* ftails,
                       const float* __restrict__ lw0, const float* __restrict__ w1,
                       const float* __restrict__ lw1, uint4* __restrict__ pkw) {
    int i = blockIdx.x * 256 + threadIdx.x;
    if (i < 384) bnsums[i] = 0.f;
    if (i < 2048) bnrep[i] = 0.f;  // 8 replicas x 128 x 2 stages
    if (i < NCB) ctails[i] = 0;
    if (i < NFB) ftails[i] = 0;
    if (i >= 1536) return;
    int set = i >> 9, r = i & 511;
    int lane = r & 63;
    int ks = (r >> 6) & 1, ct = r >> 7;
    int kbase = ks * 32 + (lane >> 4) * 8;
    int c = ct * 16 + (lane & 15);
    U4 u;
    if (set == 0) {
#pragma unroll
        for (int j = 0; j < 8; ++j) u.h[j] = __float2bfloat16(lw0[c * 64 + kbase + j]);
    } else if (set == 1) {
#pragma unroll
        for (int j = 0; j < 8; ++j) u.h[j] = __float2bfloat16(w1[(kbase + j) * 64 + c]);
    } else {
#pragma unroll
        for (int j = 0; j < 8; ++j) u.h[j] = __float2bfloat16(lw1[c * 64 + kbase + j]);
    }
    pkw[i] = u.v;
}

// pass 1: 64-way coarse bin. 4-byte records — src (17b) | dst_local (11b @ bit 17).
// LDS-compacted per-bin output + contiguous coalesced copy-out.
__global__ void __launch_bounds__(256)
k_part(const int* __restrict__ ei, unsigned int* __restrict__ cpairs,
       int* __restrict__ ctails) {
    __shared__ unsigned int s_rec[EPB];  // 5 KB compacted records
    __shared__ int cnt[NCB], lcl[NCB], lpos[NCB], off[NCB];
    int t = threadIdx.x;
    if (t < NCB) cnt[t] = 0;
    __syncthreads();
    int base = blockIdx.x * EPB;
    unsigned int loc[5];
    int blk[5];
#pragma unroll
    for (int u = 0; u < 5; ++u) {
        int e = base + u * 256 + t;
        int s = ei[e], d = ei[N_EDGES + e];
        int b = d / CB_DIV;
        blk[u] = b;
        loc[u] = (unsigned int)s | ((unsigned int)(d - b * CB_DIV) << 17);
        atomicAdd(&cnt[b], 1);
    }
    __syncthreads();
    if (t == 0) {
        int s = 0;
        for (int q = 0; q < NCB; ++q) { lcl[q] = s; s += cnt[q]; }
    }
    if (t < NCB && cnt[t] > 0) off[t] = atomicAdd(&ctails[t], cnt[t]);
    __syncthreads();
    if (t < NCB) lpos[t] = lcl[t];
    __syncthreads();
#pragma unroll
    for (int u = 0; u < 5; ++u) {
        int b = blk[u];
        int p = atomicAdd(&lpos[b], 1);
        s_rec[p] = loc[u];
    }
    __syncthreads();
    // coalesced copy-out: wave wv handles bins wv, wv+4, ...
    int wv = t >> 6, ln = t & 63;
    for (int q = wv; q < NCB; q += 4) {
        int c = cnt[q];
        if (c == 0) continue;
        unsigned int* dst = cpairs + (size_t)q * CB_CAP + off[q];
        const unsigned int* src = s_rec + lcl[q];
        for (int i = ln; i < c; i += 64) dst[i] = src[i];
    }
}

// pass 2: refine coarse bucket -> fine buckets of 64 nodes. LDS-compacted
// per-bin output, contiguous coalesced copy-out. 4B records in AND out.
__global__ void __launch_bounds__(256)
k_refine(const unsigned int* __restrict__ cpairs, const int* __restrict__ ctails,
         int* __restrict__ ftails, unsigned int* __restrict__ fpairs) {
    __shared__ unsigned int s_ed[2048];   // 8 KB strip stage
    __shared__ unsigned int s_comp[2048]; // 8 KB compacted output
    __shared__ int cnt2[32], off2[32], lcl[32], lpos[32];
    int b = blockIdx.x & 63;
    int j = blockIdx.x >> 6;
    int t = threadIdx.x;
    int cnt = ctails[b];
    int s0 = j * 2048;
    if (s0 >= cnt) return;
    int n = min(2048, cnt - s0);
    int fb0 = (b * CB_DIV) >> 6;
    int nbins = (((b + 1) * CB_DIV - 1) >> 6) - fb0 + 1;  // <= 21
    int dbase = b * CB_DIV;
    const unsigned int* lst = cpairs + (size_t)b * CB_CAP + s0;
    for (int i = t; i < n; i += 256) s_ed[i] = lst[i];
    if (t < 32) cnt2[t] = 0;
    __syncthreads();
    for (int i = t; i < n; i += 256) {
        int d = dbase + (int)(s_ed[i] >> 17);
        atomicAdd(&cnt2[(d >> 6) - fb0], 1);
    }
    __syncthreads();
    if (t == 0) {
        int s = 0;
        for (int q = 0; q < nbins; ++q) { lcl[q] = s; s += cnt2[q]; }
    }
    if (t < nbins && cnt2[t] > 0) off2[t] = atomicAdd(&ftails[fb0 + t], cnt2[t]);
    __syncthreads();
    if (t < nbins) lpos[t] = lcl[t];
    __syncthreads();
    for (int i = t; i < n; i += 256) {
        unsigned int r = s_ed[i];
        int d = dbase + (int)(r >> 17);
        int fbl = (d >> 6) - fb0;
        int p = atomicAdd(&lpos[fbl], 1);
        s_comp[p] = (r & 0x1FFFFu) | ((unsigned int)(d & 63) << 20);
    }
    __syncthreads();
    int wv = t >> 6, ln = t & 63;
    for (int q = wv; q < nbins; q += 4) {
        int c = cnt2[q];
        if (c == 0) continue;
        unsigned int* dst = fpairs + (size_t)(fb0 + q) * FB_CAP + off2[q];
        const unsigned int* src = s_comp + lcl[q];
        for (int i = ln; i < c; i += 64) dst[i] = src[i];
    }
}

// pass 3: per-fine-bucket LDS counting sort -> SEQUENTIAL src-only CSR write
// (4 B/edge; dst implied by position), per-node cursor + dinv, fused h0.
// Self-computed CSR base (block-reduces ftails[0..fb)) + shfl prefix of hist.
__global__ void __launch_bounds__(256)
k_sortfine(const unsigned int* __restrict__ fpairs, const int* __restrict__ ftails,
           int* __restrict__ src4, float* __restrict__ dinv, int* __restrict__ cursor,
           const float* __restrict__ x, const float* __restrict__ W0,
           bf16* __restrict__ hs) {
    __shared__ unsigned int stage[FB_CAP];
    __shared__ int hist[64], cur[64];
    __shared__ float sx[192], sW0[192], sdv[64];
    __shared__ int psum[4];
    int fb = blockIdx.x;
    int t = threadIdx.x;
    int lane = t & 63, wv = t >> 6;
    int cnt = ftails[fb];
    int node0 = fb * 64;
    const unsigned int* lst = fpairs + (size_t)fb * FB_CAP;
    if (t < 64) hist[t] = 0;
    if (t >= 64 && t < 256) sW0[t - 64] = W0[t - 64];  // 192 vals
    __syncthreads();
    // histogram + fbase partial + x stage (all pre-sync work)
    int part = 0;
    for (int i = t; i < fb; i += 256) part += ftails[i];
    for (int i = t; i < cnt; i += 256)
        atomicAdd(&hist[lst[i] >> 20], 1);
    for (int i = t; i < 192; i += 256) sx[i] = x[(size_t)node0 * 3 + i];
    // wave-reduce fbase partial
#pragma unroll
    for (int d = 32; d > 0; d >>= 1) part += __shfl_down(part, d, 64);
    if (lane == 0) psum[wv] = part;
    __syncthreads();  // hist atomics + psum complete
    if (t < 64) {
        int base = psum[0] + psum[1] + psum[2] + psum[3];
        int h = hist[t];
        int p = h;
#pragma unroll
        for (int d = 1; d < 64; d <<= 1) {
            int q = __shfl_up(p, d, 64);
            if (t >= d) p += q;
        }
        int excl = p - h;
        cur[t] = excl;
        cursor[node0 + t] = base + excl;
        float dv = rsqrtf((float)h + 2.0f);  // + self-loop weight 2
        dinv[node0 + t] = dv;
        sdv[t] = dv;
    }
    __syncthreads();  // cur ready; cursor written before scatter mutates cur
    for (int i = t; i < cnt; i += 256) {
        unsigned int r = lst[i];
        int p = atomicAdd(&cur[r >> 20], 1);
        stage[p] = r;
    }
    __syncthreads();
    int base = psum[0] + psum[1] + psum[2] + psum[3];
    for (int i = t; i < cnt; i += 256)
        src4[base + i] = (int)(stage[i] & 0xFFFFFu);
    // fused h0 for this bucket's 64 nodes
    for (int i = t; i < 4096; i += 256) {
        int v = i >> 6, c = i & 63;
        float h = sx[v * 3] * sW0[c] + sx[v * 3 + 1] * sW0[64 + c] + sx[v * 3 + 2] * sW0[128 + c];
        hs[(size_t)(node0 + v) * 64 + c] = __float2bfloat16(sdv[v] * h);
    }
}

// ---------------- per-stage kernels ----------------

// process one 16-edge batch (edges E..E+15) against row state (r, rend, acc)
#define PROCESS16(GV, E)                                                         \
    do {                                                                         \
        _Pragma("unroll")                                                        \
        for (int u_ = 0; u_ < 16; ++u_) {                                        \
            int eu_ = (E) + u_;                                                  \
            if (eu_ < s8) {                                                      \
                while (eu_ >= rend) {                                            \
                    float selfv_ = selfbuf[w][r][lane];                          \
                    float dvc_ = readlane_f(dval, r);                            \
                    float yf_ = fmaf(dvc_, acc + 2.f * selfv_, bc);              \
                    y[(size_t)(v0 + r) * 64 + lane] = yf_;                       \
                    bs += yf_; bss += yf_ * yf_;                                 \
                    acc = 0.f;                                                   \
                    ++r;                                                         \
                    rend = __builtin_amdgcn_readlane(cval, r + 1);               \
                }                                                                \
                acc += GV[u_];                                                   \
            }                                                                    \
        }                                                                        \
    } while (0)

// R26: CSR row-streaming aggregation with a register-explicit 2-deep x 16-wide
// gather pipeline: gathers for batch B+1 issue before processing batch B, and
// record loads run 2 batches ahead -> ~32 gathers + 16 record loads in flight
// (R22's single 32-batch was serialized by the compiler to ~12; VGPR 36).
__global__ void __launch_bounds__(512)
k_aggc(const bf16* __restrict__ hs, const int* __restrict__ src4,
       const int* __restrict__ cursor, const float* __restrict__ dinv,
       const float* __restrict__ bias, float* __restrict__ y,
       float* __restrict__ bnrep) {
    __shared__ float selfbuf[8][8][64];  // 16 KB: per-wave self rows
    int t = threadIdx.x, lane = t & 63, w = t >> 6;
    int v0 = (blockIdx.x * 8 + w) * 8;  // 1250 blocks x 8 waves x 8 nodes
    float bc = bias[lane];
    float bs = 0.f, bss = 0.f;

    // preload 9 cursors + 8 dinv lane-spread; self rows into LDS
    int cidx = v0 + lane;
    int cval = (lane <= 8) ? ((cidx < N_NODES) ? cursor[cidx] : N_EDGES) : 0;
    float dval = (lane < 8) ? dinv[cidx] : 0.f;
#pragma unroll
    for (int i = 0; i < 8; ++i)
        selfbuf[w][i][lane] = __bfloat162float(hs[(size_t)(v0 + i) * 64 + lane]);

    int s0 = __builtin_amdgcn_readlane(cval, 0);
    int s8 = __builtin_amdgcn_readlane(cval, 8);
    int r = 0;  // local row 0..7
    int rend = __builtin_amdgcn_readlane(cval, 1);
    float acc = 0.f;
    int e = s0;

    int svA[16], svB[16];
    float gvA[16], gvB[16];
    // prologue: records for batches @e and @e+16; gathers for @e
#pragma unroll
    for (int u = 0; u < 16; ++u) svA[u] = src4[min(e + u, N_EDGES - 1)];
#pragma unroll
    for (int u = 0; u < 16; ++u)
        gvA[u] = __bfloat162float(hs[(size_t)svA[u] * 64 + lane]);
#pragma unroll
    for (int u = 0; u < 16; ++u) svB[u] = src4[min(e + 16 + u, N_EDGES - 1)];

    while (e < s8) {
        // half 1: current = A
#pragma unroll
        for (int u = 0; u < 16; ++u)
            gvB[u] = __bfloat162float(hs[(size_t)svB[u] * 64 + lane]);
#pragma unroll
        for (int u = 0; u < 16; ++u) svA[u] = src4[min(e + 32 + u, N_EDGES - 1)];
        PROCESS16(gvA, e);
        e += 16;
        if (e >= s8) break;
        // half 2: current = B
#pragma unroll
        for (int u = 0; u < 16; ++u)
            gvA[u] = __bfloat162float(hs[(size_t)svA[u] * 64 + lane]);
#pragma unroll
        for (int u = 0; u < 16; ++u) svB[u] = src4[min(e + 32 + u, N_EDGES - 1)];
        PROCESS16(gvB, e);
        e += 16;
    }
    // flush remaining rows (last owned row + any trailing zero-degree rows)
    while (r < 8) {
        float selfv = selfbuf[w][r][lane];
        float dvc = readlane_f(dval, r);
        float yf = fmaf(dvc, acc + 2.f * selfv, bc);
        y[(size_t)(v0 + r) * 64 + lane] = yf;
        bs += yf; bss += yf * yf;
        acc = 0.f;
        ++r;
    }

    __shared__ float s1[512], s2[512];
    s1[t] = bs;
    s2[t] = bss;
    __syncthreads();
    if (t < 64) {
        float t1 = 0.f, t2 = 0.f;
#pragma unroll
        for (int q = 0; q < 8; ++q) {
            t1 += s1[t + q * 64];
            t2 += s2[t + q * 64];
        }
        float* dst = bnrep + (blockIdx.x & 7) * 128;  // 8 replicas cut contention
        atomicAdd(&dst[t], t1);
        atomicAdd(&dst[64 + t], t2);
    }
}

// MFMA k_post64 (R25, unchanged). BN+pool+leaky -> bf16 LDS tile ->
// 16x16x32 bf16 MFMA matmuls; wave owns a 16-node stripe.
template <int P, int MODE>
__global__ void __launch_bounds__(256)
k_post64(const float* __restrict__ y, const float* __restrict__ dinv,
         const float* __restrict__ bnrep,
         const float* __restrict__ g, const float* __restrict__ bb,
         const uint4* __restrict__ lwpk, const float* __restrict__ lb,
         const uint4* __restrict__ Wnpk, const float* __restrict__ Wnf,
         bf16* __restrict__ hsout, float4* __restrict__ hs3) {
    __shared__ short s_a[4][16][72];  // per-wave bf16 tile [node][ch], 144B rows
    __shared__ float s_Wnf[MODE == 1 ? 192 : 1];
    int t = threadIdx.x, w = t >> 6, lane = t & 63;
    // B-fragments in registers (coalesced 16B/lane)
    bf16x8 bw[4][2];
#pragma unroll
    for (int ct = 0; ct < 4; ++ct)
#pragma unroll
        for (int ks = 0; ks < 2; ++ks)
            bw[ct][ks] = *(const bf16x8*)&lwpk[(ct * 2 + ks) * 64 + lane];
    bf16x8 wn[4][2];
    if constexpr (MODE == 0) {
#pragma unroll
        for (int ct = 0; ct < 4; ++ct)
#pragma unroll
            for (int ks = 0; ks < 2; ++ks)
                wn[ct][ks] = *(const bf16x8*)&Wnpk[(ct * 2 + ks) * 64 + lane];
    } else {
        for (int i = t; i < 192; i += 256) s_Wnf[i] = Wnf[i];
    }
    float msum = 0.f, vsum = 0.f;
#pragma unroll
    for (int r = 0; r < 8; ++r) {
        msum += bnrep[r * 128 + lane];
        vsum += bnrep[r * 128 + 64 + lane];
    }
    float inv_n = 1.0f / (float)N_NODES;
    float mean = msum * inv_n;
    float var = fmaxf(vsum * inv_n - mean * mean, 0.f);
    float sc = g[lane] * rsqrtf(var + 1e-5f);
    float sh = bb[lane] - mean * sc;
    float lbv[4];
#pragma unroll
    for (int ct = 0; ct < 4; ++ct) lbv[ct] = lb[ct * 16 + (lane & 15)];
    int row = lane & 15, kg = lane >> 4;
    __syncthreads();  // s_Wnf ready (MODE 1)

    for (int tile = blockIdx.x; tile < N_NODES / 64; tile += gridDim.x) {
        int nbase = tile * 64 + w * 16;
        // phase 1: BN + pool + leaky; bf16 into own wave's LDS tile
#pragma unroll 4
        for (int i = 0; i < 16; ++i) {
            float z = fmaf(sc, y[(size_t)(nbase + i) * 64 + lane], sh);
            float m = z;
#pragma unroll
            for (int d = 1; d <= P; ++d) {
                float up = __shfl(z, lane + d);
                float dn = __shfl(z, lane - d);
                m = fmaxf(m, (lane + d < 64) ? up : -INFINITY);
                m = fmaxf(m, (lane - d >= 0) ? dn : -INFINITY);
            }
            s_a[w][i][lane] = bf16bits(leaky(m));
        }
        __syncthreads();
        // phase 2: o = leaky(a @ lwT + lb) via MFMA
        f32x4 acc[4];
#pragma unroll
        for (int ct = 0; ct < 4; ++ct) acc[ct] = (f32x4){0.f, 0.f, 0.f, 0.f};
#pragma unroll
        for (int ks = 0; ks < 2; ++ks) {
            bf16x8 af = *(bf16x8*)&s_a[w][row][ks * 32 + kg * 8];
#pragma unroll
            for (int ct = 0; ct < 4; ++ct)
                acc[ct] = __builtin_amdgcn_mfma_f32_16x16x32_bf16(af, bw[ct][ks], acc[ct], 0, 0, 0);
        }
        float o[4][4];
#pragma unroll
        for (int ct = 0; ct < 4; ++ct)
#pragma unroll
            for (int j = 0; j < 4; ++j)
                o[ct][j] = leaky(acc[ct][j] + lbv[ct]);

        if constexpr (MODE == 0) {
            // o back to LDS as bf16 (C-layout -> [node][ch]); same-wave, barrier'd
            __syncthreads();
#pragma unroll
            for (int ct = 0; ct < 4; ++ct)
#pragma unroll
                for (int j = 0; j < 4; ++j)
                    s_a[w][kg * 4 + j][ct * 16 + (lane & 15)] = bf16bits(o[ct][j]);
            __syncthreads();
            f32x4 acc2[4];
#pragma unroll
            for (int ct = 0; ct < 4; ++ct) acc2[ct] = (f32x4){0.f, 0.f, 0.f, 0.f};
#pragma unroll
            for (int ks = 0; ks < 2; ++ks) {
                bf16x8 af = *(bf16x8*)&s_a[w][row][ks * 32 + kg * 8];
#pragma unroll
                for (int ct = 0; ct < 4; ++ct)
                    acc2[ct] = __builtin_amdgcn_mfma_f32_16x16x32_bf16(af, wn[ct][ks], acc2[ct], 0, 0, 0);
            }
            // scale by dinv, stage bf16 in LDS, then fully-coalesced store
            float dvj[4];
#pragma unroll
            for (int j = 0; j < 4; ++j) dvj[j] = dinv[nbase + kg * 4 + j];
            __syncthreads();
#pragma unroll
            for (int ct = 0; ct < 4; ++ct)
#pragma unroll
                for (int j = 0; j < 4; ++j)
                    s_a[w][kg * 4 + j][ct * 16 + (lane & 15)] = bf16bits(dvj[j] * acc2[ct][j]);
            __syncthreads();
            int nd = lane >> 2, c0 = (lane & 3) * 8;
#pragma unroll
            for (int pass = 0; pass < 2; ++pass)
                *(uint4*)&hsout[(size_t)(nbase + nd) * 64 + c0 + pass * 32] =
                    *(uint4*)&s_a[w][nd][c0 + pass * 32];
        } else {
            // proj: h3 = o @ w2 (64x3); per-lane partials over its 4 chs,
            // xor-shuffle reduce across the 16 lanes sharing a row-group
            float p[4][3];
#pragma unroll
            for (int j = 0; j < 4; ++j)
#pragma unroll
                for (int m = 0; m < 3; ++m) p[j][m] = 0.f;
            int myc = lane & 15;
#pragma unroll
            for (int ct = 0; ct < 4; ++ct) {
                int ch = ct * 16 + myc;
                float w0 = s_Wnf[ch * 3 + 0], w1 = s_Wnf[ch * 3 + 1], w2v = s_Wnf[ch * 3 + 2];
#pragma unroll
                for (int j = 0; j < 4; ++j) {
                    p[j][0] = fmaf(o[ct][j], w0, p[j][0]);
                    p[j][1] = fmaf(o[ct][j], w1, p[j][1]);
                    p[j][2] = fmaf(o[ct][j], w2v, p[j][2]);
                }
            }
#pragma unroll
            for (int mask = 1; mask <= 8; mask <<= 1)
#pragma unroll
                for (int j = 0; j < 4; ++j)
#pragma unroll
                    for (int m = 0; m < 3; ++m)
                        p[j][m] += __shfl_xor(p[j][m], mask, 64);
            if (myc == 0) {
#pragma unroll
                for (int j = 0; j < 4; ++j) {
                    int node = nbase + kg * 4 + j;
                    float dv = dinv[node];
                    hs3[node] = make_float4(dv * p[j][0], dv * p[j][1], dv * p[j][2], 0.f);
                }
            }
            __syncthreads();  // protect s_a before next tile's phase-1
        }
    }
}

// stage-2: aggregation (thread-per-node over CSR rowstart) + final y3 + BN stats.
__global__ void __launch_bounds__(256)
k_agg3(const float4* __restrict__ hs3, const int* __restrict__ cursor,
       const int* __restrict__ src4, const float* __restrict__ dinv,
       const float* __restrict__ b2, float4* __restrict__ y3,
       float* __restrict__ bnsum) {
    int v = blockIdx.x * blockDim.x + threadIdx.x;
    float y0 = 0.f, y1 = 0.f, y2 = 0.f;
    bool valid = v < N_NODES;
    if (valid) {
        int start = cursor[v];
        int end = (v + 1 < N_NODES) ? cursor[v + 1] : N_EDGES;
        float a0 = 0.f, a1 = 0.f, a2 = 0.f;
        int e = start;
        for (; e + 4 <= end; e += 4) {
            int c[4];
#pragma unroll
            for (int u = 0; u < 4; ++u) c[u] = src4[e + u];
#pragma unroll
            for (int u = 0; u < 4; ++u) {
                float4 h = hs3[c[u]];
                a0 += h.x; a1 += h.y; a2 += h.z;
            }
        }
        for (; e < end; ++e) {
            float4 h = hs3[src4[e]];
            a0 += h.x; a1 += h.y; a2 += h.z;
        }
        float dv = dinv[v];
        float4 hsv = hs3[v];
        y0 = dv * (a0 + 2.f * hsv.x) + b2[0];
        y1 = dv * (a1 + 2.f * hsv.y) + b2[1];
        y2 = dv * (a2 + 2.f * hsv.z) + b2[2];
        y3[v] = make_float4(y0, y1, y2, 0.f);
    }
    __shared__ float sm[256];
    float vals[6] = {y0, y1, y2, y0 * y0, y1 * y1, y2 * y2};
    for (int c = 0; c < 6; ++c) {
        sm[threadIdx.x] = valid ? vals[c] : 0.f;
        __syncthreads();
        for (int off = 128; off > 0; off >>= 1) {
            if (threadIdx.x < off) sm[threadIdx.x] += sm[threadIdx.x + off];
            __syncthreads();
        }
        if (threadIdx.x == 0) atomicAdd(&bnsum[c], sm[0]);
        __syncthreads();
    }
}

// final stage post: BN + pool(3,1) + leaky + 3x3 linear + leaky
__global__ void k_post3(const float4* __restrict__ y3, const float* __restrict__ bnsum,
                        const float* __restrict__ g, const float* __restrict__ bb,
                        const float* __restrict__ lw, const float* __restrict__ lb,
                        float* __restrict__ out) {
    int v = blockIdx.x * blockDim.x + threadIdx.x;
    if (v >= N_NODES) return;
    float inv_n = 1.0f / (float)N_NODES;
    float sc[3], sh[3];
#pragma unroll
    for (int c = 0; c < 3; ++c) {
        float mean = bnsum[c] * inv_n;
        float var = fmaxf(bnsum[3 + c] * inv_n - mean * mean, 0.f);
        sc[c] = g[c] * rsqrtf(var + 1e-5f);
        sh[c] = bb[c] - mean * sc[c];
    }
    float4 y = y3[v];
    float z0 = fmaf(y.x, sc[0], sh[0]);
    float z1 = fmaf(y.y, sc[1], sh[1]);
    float z2 = fmaf(y.z, sc[2], sh[2]);
    float p0 = fmaxf(z0, z1);
    float p1 = fmaxf(p0, z2);
    float p2 = fmaxf(z1, z2);
    float a0 = leaky(p0), a1 = leaky(p1), a2 = leaky(p2);
    float o0 = leaky(lb[0] + a0 * lw[0] + a1 * lw[1] + a2 * lw[2]);
    float o1 = leaky(lb[1] + a0 * lw[3] + a1 * lw[4] + a2 * lw[5]);
    float o2 = leaky(lb[2] + a0 * lw[6] + a1 * lw[7] + a2 * lw[8]);
    out[v * 3 + 0] = o0;
    out[v * 3 + 1] = o1;
    out[v * 3 + 2] = o2;
}

// ---------------- launcher ----------------

extern "C" void kernel_launch(void* const* d_in, const int* in_sizes, int n_in,
                              void* d_out, int out_size, void* d_ws, size_t ws_size,
                              hipStream_t stream) {
    const float* x  = (const float*)d_in[0];
    const int*   ei = (const int*)d_in[1];
    const float* w0 = (const float*)d_in[2];
    const float* b0 = (const float*)d_in[3];
    const float* g0 = (const float*)d_in[4];
    const float* bb0 = (const float*)d_in[5];
    const float* lw0 = (const float*)d_in[6];
    const float* lb0 = (const float*)d_in[7];
    const float* w1 = (const float*)d_in[8];
    const float* b1 = (const float*)d_in[9];
    const float* g1 = (const float*)d_in[10];
    const float* bb1 = (const float*)d_in[11];
    const float* lw1 = (const float*)d_in[12];
    const float* lb1 = (const float*)d_in[13];
    const float* w2 = (const float*)d_in[14];
    const float* b2 = (const float*)d_in[15];
    const float* g2 = (const float*)d_in[16];
    const float* bb2 = (const float*)d_in[17];
    const float* lw2 = (const float*)d_in[18];
    const float* lb2 = (const float*)d_in[19];
    float* out = (float*)d_out;

    // workspace layout (16B-aligned first) — byte-identical to the 416us baseline
    char* w = (char*)d_ws;
    float* yagg = (float*)w;       w += (size_t)N_NODES * 64 * 4;        // 20.48 MB (pre-BN y)
    int* src4 = (int*)w;           w += (size_t)N_EDGES * 8;             // first 5.12MB of ex-ed2 slot
    unsigned int* fpairs = (unsigned int*)w; w += (size_t)NFB * FB_CAP * 4;  // 6.4 MB
    bf16* hs = (bf16*)w;           w += (size_t)N_NODES * 64 * 2;        // 10.24 MB
    float4* hs3 = (float4*)w;      w += (size_t)N_NODES * 16;            // 1.28 MB
    float4* y3 = (float4*)w;       w += (size_t)N_NODES * 16;            // 1.28 MB
    int* fbase = (int*)w;          w += (size_t)N_NODES * 4;             // (slot kept; bnrep lives here)
    float* dinv = (float*)w;       w += (size_t)N_NODES * 4;
    int* cursor = (int*)w;         w += (size_t)N_NODES * 4;
    int* partial = (int*)w;        w += 512 * 4;                         // unused (layout kept)
    float* bnsum = (float*)w;      w += 384 * 4;
    int* ctails = (int*)w;         w += NCB * 4;
    int* ftails = (int*)w;         w += NFB * 4;
    (void)partial;
    // cpairs overlays yagg (dead after k_refine, before k_aggc writes y) — 5.25 MB
    unsigned int* cpairs = (unsigned int*)yagg;
    // pkw overlays y3 (pkw last read in stage-1 k_post64; y3 first written by k_agg3)
    uint4* pkw = (uint4*)y3;
    // BN-stat replicas carved from the fbase slot (+16 KB)
    float* bnrep = (float*)((char*)fbase + 16384);  // 2 stages x 8 reps x 128 = 8 KB

    const int NB = (N_NODES + 255) / 256;  // 313

    // --- graph/CSR setup: coarse bin -> refine -> LDS sort+h0 (self-based) ---
    k_init<<<8, 256, 0, stream>>>(bnsum, bnrep, ctails, ftails, lw0, w1, lw1, pkw);
    k_part<<<N_EDGES / EPB, 256, 0, stream>>>(ei, cpairs, ctails);
    k_refine<<<64 * 16, 256, 0, stream>>>(cpairs, ctails, ftails, fpairs);
    k_sortfine<<<NFB, 256, 0, stream>>>(fpairs, ftails, src4, dinv, cursor,
                                        x, w0, hs);

    // --- stage 0 ---
    k_aggc<<<1250, 512, 0, stream>>>(hs, src4, cursor, dinv, b0, yagg, bnrep);
    k_post64<1, 0><<<1250, 256, 0, stream>>>(yagg, dinv, bnrep, g0, bb0,
                                             pkw, lb0, pkw + 512, nullptr,
                                             hs, nullptr);

    // --- stage 1 ---
    k_aggc<<<1250, 512, 0, stream>>>(hs, src4, cursor, dinv, b1, yagg, bnrep + 1024);
    k_post64<2, 1><<<1250, 256, 0, stream>>>(yagg, dinv, bnrep + 1024, g1, bb1,
                                             pkw + 1024, lb1, nullptr, w2,
                                             nullptr, hs3);

    // --- stage 2 (C=3): agg + BN stats fused ---
    k_agg3<<<NB, 256, 0, stream>>>(hs3, cursor, src4, dinv, b2, y3, bnsum + 256);
    k_post3<<<NB, 256, 0, stream>>>(y3, bnsum + 256, g2, bb2, lw2, lb2, out);
}

// Round 17
// 267.757 us; speedup vs baseline: 1.0698x; 1.0698x over previous
//
#include <hip/hip_runtime.h>
#include <hip/hip_bf16.h>
#include <math.h>

#define N_NODES 80000
#define N_EDGES 1280000
#define NCB 64
#define CB_DIV 1250                 // coarse bucket = dst / 1250 -> 0..63
#define CB_CAP 21000                // mean 20000, +7 sigma
#define NFB 1250                    // fine bucket = dst >> 6 (64 nodes each)
#define FB_CAP 1280                 // mean 1024, +8 sigma
#define EPB 1280                    // edges per k_part block (grid 1000)

typedef __hip_bfloat16 bf16;
typedef __attribute__((ext_vector_type(8))) short bf16x8;   // MFMA A/B frag (4 VGPR)
typedef __attribute__((ext_vector_type(4))) float f32x4;    // MFMA C/D frag

__device__ __forceinline__ float leaky(float x) { return x >= 0.f ? x : 0.01f * x; }

// readlane for float: MUST bit-cast (the builtin is (int,int); passing float
// value-converts and destroys the data — R21's correctness bug).
__device__ __forceinline__ float readlane_f(float v, int l) {
    return __int_as_float(__builtin_amdgcn_readlane(__float_as_int(v), l));
}

__device__ __forceinline__ short bf16bits(float x) {
    bf16 b = __float2bfloat16(x);
    return *(short*)&b;
}

union U4 { uint4 v; bf16 h[8]; };

// ---------------- setup kernels ----------------

// merged zero + weight-pack (one launch). Weights packed in MFMA B-FRAGMENT
// order — frag f = (ct*2+ks)*64+lane holds B[k][c] for
// k = ks*32+(lane>>4)*8+j, c = ct*16+(lane&15).
// pkw[0..511] = lw0T frags; pkw[512..1023] = w1 frags; pkw[1024..1535] = lw1T frags
// NOTE: pkw overlays y3 (disjoint liveness: pkw dead before k_agg3 writes y3)
__global__ void k_init(float* bnsums, float* bnrep, int* ctails, int* ftails,
                       const float* __restrict__ lw0, const float* __restrict__ w1,
                       const float* __restrict__ lw1, uint4* __restrict__ pkw) {
    int i = blockIdx.x * 256 + threadIdx.x;
    if (i < 384) bnsums[i] = 0.f;
    if (i < 2048) bnrep[i] = 0.f;  // 8 replicas x 128 x 2 stages
    if (i < NCB) ctails[i] = 0;
    if (i < NFB) ftails[i] = 0;
    if (i >= 1536) return;
    int set = i >> 9, r = i & 511;
    int lane = r & 63;
    int ks = (r >> 6) & 1, ct = r >> 7;
    int kbase = ks * 32 + (lane >> 4) * 8;
    int c = ct * 16 + (lane & 15);
    U4 u;
    if (set == 0) {
#pragma unroll
        for (int j = 0; j < 8; ++j) u.h[j] = __float2bfloat16(lw0[c * 64 + kbase + j]);
    } else if (set == 1) {
#pragma unroll
        for (int j = 0; j < 8; ++j) u.h[j] = __float2bfloat16(w1[(kbase + j) * 64 + c]);
    } else {
#pragma unroll
        for (int j = 0; j < 8; ++j) u.h[j] = __float2bfloat16(lw1[c * 64 + kbase + j]);
    }
    pkw[i] = u.v;
}

// pass 1: 64-way coarse bin. 4-byte records — src (17b) | dst_local (11b @ bit 17).
// LDS-compacted per-bin output + contiguous coalesced copy-out.
__global__ void __launch_bounds__(256)
k_part(const int* __restrict__ ei, unsigned int* __restrict__ cpairs,
       int* __restrict__ ctails) {
    __shared__ unsigned int s_rec[EPB];  // 5 KB compacted records
    __shared__ int cnt[NCB], lcl[NCB], lpos[NCB], off[NCB];
    int t = threadIdx.x;
    if (t < NCB) cnt[t] = 0;
    __syncthreads();
    int base = blockIdx.x * EPB;
    unsigned int loc[5];
    int blk[5];
#pragma unroll
    for (int u = 0; u < 5; ++u) {
        int e = base + u * 256 + t;
        int s = ei[e], d = ei[N_EDGES + e];
        int b = d / CB_DIV;
        blk[u] = b;
        loc[u] = (unsigned int)s | ((unsigned int)(d - b * CB_DIV) << 17);
        atomicAdd(&cnt[b], 1);
    }
    __syncthreads();
    if (t == 0) {
        int s = 0;
        for (int q = 0; q < NCB; ++q) { lcl[q] = s; s += cnt[q]; }
    }
    if (t < NCB && cnt[t] > 0) off[t] = atomicAdd(&ctails[t], cnt[t]);
    __syncthreads();
    if (t < NCB) lpos[t] = lcl[t];
    __syncthreads();
#pragma unroll
    for (int u = 0; u < 5; ++u) {
        int b = blk[u];
        int p = atomicAdd(&lpos[b], 1);
        s_rec[p] = loc[u];
    }
    __syncthreads();
    // coalesced copy-out: wave wv handles bins wv, wv+4, ...
    int wv = t >> 6, ln = t & 63;
    for (int q = wv; q < NCB; q += 4) {
        int c = cnt[q];
        if (c == 0) continue;
        unsigned int* dst = cpairs + (size_t)q * CB_CAP + off[q];
        const unsigned int* src = s_rec + lcl[q];
        for (int i = ln; i < c; i += 64) dst[i] = src[i];
    }
}

// pass 2: refine coarse bucket -> fine buckets of 64 nodes. LDS-compacted
// per-bin output, contiguous coalesced copy-out. 4B records in AND out.
__global__ void __launch_bounds__(256)
k_refine(const unsigned int* __restrict__ cpairs, const int* __restrict__ ctails,
         int* __restrict__ ftails, unsigned int* __restrict__ fpairs) {
    __shared__ unsigned int s_ed[2048];   // 8 KB strip stage
    __shared__ unsigned int s_comp[2048]; // 8 KB compacted output
    __shared__ int cnt2[32], off2[32], lcl[32], lpos[32];
    int b = blockIdx.x & 63;
    int j = blockIdx.x >> 6;
    int t = threadIdx.x;
    int cnt = ctails[b];
    int s0 = j * 2048;
    if (s0 >= cnt) return;
    int n = min(2048, cnt - s0);
    int fb0 = (b * CB_DIV) >> 6;
    int nbins = (((b + 1) * CB_DIV - 1) >> 6) - fb0 + 1;  // <= 21
    int dbase = b * CB_DIV;
    const unsigned int* lst = cpairs + (size_t)b * CB_CAP + s0;
    for (int i = t; i < n; i += 256) s_ed[i] = lst[i];
    if (t < 32) cnt2[t] = 0;
    __syncthreads();
    for (int i = t; i < n; i += 256) {
        int d = dbase + (int)(s_ed[i] >> 17);
        atomicAdd(&cnt2[(d >> 6) - fb0], 1);
    }
    __syncthreads();
    if (t == 0) {
        int s = 0;
        for (int q = 0; q < nbins; ++q) { lcl[q] = s; s += cnt2[q]; }
    }
    if (t < nbins && cnt2[t] > 0) off2[t] = atomicAdd(&ftails[fb0 + t], cnt2[t]);
    __syncthreads();
    if (t < nbins) lpos[t] = lcl[t];
    __syncthreads();
    for (int i = t; i < n; i += 256) {
        unsigned int r = s_ed[i];
        int d = dbase + (int)(r >> 17);
        int fbl = (d >> 6) - fb0;
        int p = atomicAdd(&lpos[fbl], 1);
        s_comp[p] = (r & 0x1FFFFu) | ((unsigned int)(d & 63) << 20);
    }
    __syncthreads();
    int wv = t >> 6, ln = t & 63;
    for (int q = wv; q < nbins; q += 4) {
        int c = cnt2[q];
        if (c == 0) continue;
        unsigned int* dst = fpairs + (size_t)(fb0 + q) * FB_CAP + off2[q];
        const unsigned int* src = s_comp + lcl[q];
        for (int i = ln; i < c; i += 64) dst[i] = src[i];
    }
}

// pass 3: per-fine-bucket LDS counting sort -> SEQUENTIAL src-only CSR write
// (4 B/edge; dst implied by position), per-node cursor + dinv, fused h0.
// Self-computed CSR base (block-reduces ftails[0..fb)) + shfl prefix of hist.
__global__ void __launch_bounds__(256)
k_sortfine(const unsigned int* __restrict__ fpairs, const int* __restrict__ ftails,
           int* __restrict__ src4, float* __restrict__ dinv, int* __restrict__ cursor,
           const float* __restrict__ x, const float* __restrict__ W0,
           bf16* __restrict__ hs) {
    __shared__ unsigned int stage[FB_CAP];
    __shared__ int hist[64], cur[64];
    __shared__ float sx[192], sW0[192], sdv[64];
    __shared__ int psum[4];
    int fb = blockIdx.x;
    int t = threadIdx.x;
    int lane = t & 63, wv = t >> 6;
    int cnt = ftails[fb];
    int node0 = fb * 64;
    const unsigned int* lst = fpairs + (size_t)fb * FB_CAP;
    if (t < 64) hist[t] = 0;
    if (t >= 64 && t < 256) sW0[t - 64] = W0[t - 64];  // 192 vals
    __syncthreads();
    // histogram + fbase partial + x stage (all pre-sync work)
    int part = 0;
    for (int i = t; i < fb; i += 256) part += ftails[i];
    for (int i = t; i < cnt; i += 256)
        atomicAdd(&hist[lst[i] >> 20], 1);
    for (int i = t; i < 192; i += 256) sx[i] = x[(size_t)node0 * 3 + i];
    // wave-reduce fbase partial
#pragma unroll
    for (int d = 32; d > 0; d >>= 1) part += __shfl_down(part, d, 64);
    if (lane == 0) psum[wv] = part;
    __syncthreads();  // hist atomics + psum complete
    if (t < 64) {
        int base = psum[0] + psum[1] + psum[2] + psum[3];
        int h = hist[t];
        int p = h;
#pragma unroll
        for (int d = 1; d < 64; d <<= 1) {
            int q = __shfl_up(p, d, 64);
            if (t >= d) p += q;
        }
        int excl = p - h;
        cur[t] = excl;
        cursor[node0 + t] = base + excl;
        float dv = rsqrtf((float)h + 2.0f);  // + self-loop weight 2
        dinv[node0 + t] = dv;
        sdv[t] = dv;
    }
    __syncthreads();  // cur ready; cursor written before scatter mutates cur
    for (int i = t; i < cnt; i += 256) {
        unsigned int r = lst[i];
        int p = atomicAdd(&cur[r >> 20], 1);
        stage[p] = r;
    }
    __syncthreads();
    int base = psum[0] + psum[1] + psum[2] + psum[3];
    for (int i = t; i < cnt; i += 256)
        src4[base + i] = (int)(stage[i] & 0xFFFFFu);
    // fused h0 for this bucket's 64 nodes
    for (int i = t; i < 4096; i += 256) {
        int v = i >> 6, c = i & 63;
        float h = sx[v * 3] * sW0[c] + sx[v * 3 + 1] * sW0[64 + c] + sx[v * 3 + 2] * sW0[128 + c];
        hs[(size_t)(node0 + v) * 64 + c] = __float2bfloat16(sdv[v] * h);
    }
}

// ---------------- per-stage kernels ----------------

// CSR row-streaming aggregation (R24/R25 structure — best measured: 45.6us).
// Wave owns 8 consecutive nodes, streams its contiguous edge range in UNIFORM
// 32-wide gather batches. Row boundaries via lane-spread cursors + readlane
// (SALU); self-rows pre-staged in private LDS.
__global__ void __launch_bounds__(512)
k_aggc(const bf16* __restrict__ hs, const int* __restrict__ src4,
       const int* __restrict__ cursor, const float* __restrict__ dinv,
       const float* __restrict__ bias, float* __restrict__ y,
       float* __restrict__ bnrep) {
    __shared__ float selfbuf[8][8][64];  // 16 KB: per-wave self rows
    int t = threadIdx.x, lane = t & 63, w = t >> 6;
    int v0 = (blockIdx.x * 8 + w) * 8;  // 1250 blocks x 8 waves x 8 nodes
    float bc = bias[lane];
    float bs = 0.f, bss = 0.f;

    // preload 9 cursors + 8 dinv lane-spread; self rows into LDS
    int cidx = v0 + lane;
    int cval = (lane <= 8) ? ((cidx < N_NODES) ? cursor[cidx] : N_EDGES) : 0;
    float dval = (lane < 8) ? dinv[cidx] : 0.f;
#pragma unroll
    for (int i = 0; i < 8; ++i)
        selfbuf[w][i][lane] = __bfloat162float(hs[(size_t)(v0 + i) * 64 + lane]);

    int s0 = __builtin_amdgcn_readlane(cval, 0);
    int s8 = __builtin_amdgcn_readlane(cval, 8);
    int r = 0;  // local row 0..7
    int rend = __builtin_amdgcn_readlane(cval, 1);
    float acc = 0.f;
    int e = s0;
    while (e < s8) {
        int sv[32];
        float gv[32];
        if (e + 32 <= s8) {  // fast path: no clamping (s8 <= N_EDGES)
#pragma unroll
            for (int u = 0; u < 32; ++u) sv[u] = src4[e + u];
        } else {
#pragma unroll
            for (int u = 0; u < 32; ++u) sv[u] = src4[min(e + u, N_EDGES - 1)];
        }
#pragma unroll
        for (int u = 0; u < 32; ++u)
            gv[u] = __bfloat162float(hs[(size_t)sv[u] * 64 + lane]);
#pragma unroll
        for (int u = 0; u < 32; ++u) {
            int eu = e + u;
            if (eu < s8) {                 // wave-uniform scalar guard
                while (eu >= rend) {       // flush completed row(s)
                    float selfv = selfbuf[w][r][lane];
                    float dvc = readlane_f(dval, r);
                    float yf = fmaf(dvc, acc + 2.f * selfv, bc);
                    y[(size_t)(v0 + r) * 64 + lane] = yf;
                    bs += yf; bss += yf * yf;
                    acc = 0.f;
                    ++r;
                    rend = __builtin_amdgcn_readlane(cval, r + 1);
                }
                acc += gv[u];
            }
        }
        e += 32;
    }
    // flush remaining rows (last owned row + any trailing zero-degree rows)
    while (r < 8) {
        float selfv = selfbuf[w][r][lane];
        float dvc = readlane_f(dval, r);
        float yf = fmaf(dvc, acc + 2.f * selfv, bc);
        y[(size_t)(v0 + r) * 64 + lane] = yf;
        bs += yf; bss += yf * yf;
        acc = 0.f;
        ++r;
    }

    __shared__ float s1[512], s2[512];
    s1[t] = bs;
    s2[t] = bss;
    __syncthreads();
    if (t < 64) {
        float t1 = 0.f, t2 = 0.f;
#pragma unroll
        for (int q = 0; q < 8; ++q) {
            t1 += s1[t + q * 64];
            t2 += s2[t + q * 64];
        }
        float* dst = bnrep + (blockIdx.x & 7) * 128;  // 8 replicas cut contention
        atomicAdd(&dst[t], t1);
        atomicAdd(&dst[64 + t], t2);
    }
}

// MFMA k_post64 (R25). BN+pool+leaky (VALU, lane=channel) -> bf16 LDS tile ->
// 16x16x32 bf16 MFMA matmuls. Wave owns a 16-node stripe (4 col-tiles x K=64
// = 8 MFMA per matmul). A-frag: lane holds A[l&15][(l>>4)*8..+8]. B-frags
// pre-packed by k_init, kept in registers. C/D: col=lane&15, row=(lane>>4)*4+j.
template <int P, int MODE>
__global__ void __launch_bounds__(256)
k_post64(const float* __restrict__ y, const float* __restrict__ dinv,
         const float* __restrict__ bnrep,
         const float* __restrict__ g, const float* __restrict__ bb,
         const uint4* __restrict__ lwpk, const float* __restrict__ lb,
         const uint4* __restrict__ Wnpk, const float* __restrict__ Wnf,
         bf16* __restrict__ hsout, float4* __restrict__ hs3) {
    __shared__ short s_a[4][16][72];  // per-wave bf16 tile [node][ch], 144B rows
    __shared__ float s_Wnf[MODE == 1 ? 192 : 1];
    int t = threadIdx.x, w = t >> 6, lane = t & 63;
    // B-fragments in registers (coalesced 16B/lane)
    bf16x8 bw[4][2];
#pragma unroll
    for (int ct = 0; ct < 4; ++ct)
#pragma unroll
        for (int ks = 0; ks < 2; ++ks)
            bw[ct][ks] = *(const bf16x8*)&lwpk[(ct * 2 + ks) * 64 + lane];
    bf16x8 wn[4][2];
    if constexpr (MODE == 0) {
#pragma unroll
        for (int ct = 0; ct < 4; ++ct)
#pragma unroll
            for (int ks = 0; ks < 2; ++ks)
                wn[ct][ks] = *(const bf16x8*)&Wnpk[(ct * 2 + ks) * 64 + lane];
    } else {
        for (int i = t; i < 192; i += 256) s_Wnf[i] = Wnf[i];
    }
    float msum = 0.f, vsum = 0.f;
#pragma unroll
    for (int r = 0; r < 8; ++r) {
        msum += bnrep[r * 128 + lane];
        vsum += bnrep[r * 128 + 64 + lane];
    }
    float inv_n = 1.0f / (float)N_NODES;
    float mean = msum * inv_n;
    float var = fmaxf(vsum * inv_n - mean * mean, 0.f);
    float sc = g[lane] * rsqrtf(var + 1e-5f);
    float sh = bb[lane] - mean * sc;
    float lbv[4];
#pragma unroll
    for (int ct = 0; ct < 4; ++ct) lbv[ct] = lb[ct * 16 + (lane & 15)];
    int row = lane & 15, kg = lane >> 4;
    __syncthreads();  // s_Wnf ready (MODE 1)

    for (int tile = blockIdx.x; tile < N_NODES / 64; tile += gridDim.x) {
        int nbase = tile * 64 + w * 16;
        // phase 1: BN + pool + leaky; bf16 into own wave's LDS tile
#pragma unroll 4
        for (int i = 0; i < 16; ++i) {
            float z = fmaf(sc, y[(size_t)(nbase + i) * 64 + lane], sh);
            float m = z;
#pragma unroll
            for (int d = 1; d <= P; ++d) {
                float up = __shfl(z, lane + d);
                float dn = __shfl(z, lane - d);
                m = fmaxf(m, (lane + d < 64) ? up : -INFINITY);
                m = fmaxf(m, (lane - d >= 0) ? dn : -INFINITY);
            }
            s_a[w][i][lane] = bf16bits(leaky(m));
        }
        __syncthreads();
        // phase 2: o = leaky(a @ lwT + lb) via MFMA
        f32x4 acc[4];
#pragma unroll
        for (int ct = 0; ct < 4; ++ct) acc[ct] = (f32x4){0.f, 0.f, 0.f, 0.f};
#pragma unroll
        for (int ks = 0; ks < 2; ++ks) {
            bf16x8 af = *(bf16x8*)&s_a[w][row][ks * 32 + kg * 8];
#pragma unroll
            for (int ct = 0; ct < 4; ++ct)
                acc[ct] = __builtin_amdgcn_mfma_f32_16x16x32_bf16(af, bw[ct][ks], acc[ct], 0, 0, 0);
        }
        float o[4][4];
#pragma unroll
        for (int ct = 0; ct < 4; ++ct)
#pragma unroll
            for (int j = 0; j < 4; ++j)
                o[ct][j] = leaky(acc[ct][j] + lbv[ct]);

        if constexpr (MODE == 0) {
            // o back to LDS as bf16 (C-layout -> [node][ch]); same-wave, barrier'd
            __syncthreads();
#pragma unroll
            for (int ct = 0; ct < 4; ++ct)
#pragma unroll
                for (int j = 0; j < 4; ++j)
                    s_a[w][kg * 4 + j][ct * 16 + (lane & 15)] = bf16bits(o[ct][j]);
            __syncthreads();
            f32x4 acc2[4];
#pragma unroll
            for (int ct = 0; ct < 4; ++ct) acc2[ct] = (f32x4){0.f, 0.f, 0.f, 0.f};
#pragma unroll
            for (int ks = 0; ks < 2; ++ks) {
                bf16x8 af = *(bf16x8*)&s_a[w][row][ks * 32 + kg * 8];
#pragma unroll
                for (int ct = 0; ct < 4; ++ct)
                    acc2[ct] = __builtin_amdgcn_mfma_f32_16x16x32_bf16(af, wn[ct][ks], acc2[ct], 0, 0, 0);
            }
            // scale by dinv, stage bf16 in LDS, then fully-coalesced store
            float dvj[4];
#pragma unroll
            for (int j = 0; j < 4; ++j) dvj[j] = dinv[nbase + kg * 4 + j];
            __syncthreads();
#pragma unroll
            for (int ct = 0; ct < 4; ++ct)
#pragma unroll
                for (int j = 0; j < 4; ++j)
                    s_a[w][kg * 4 + j][ct * 16 + (lane & 15)] = bf16bits(dvj[j] * acc2[ct][j]);
            __syncthreads();
            int nd = lane >> 2, c0 = (lane & 3) * 8;
#pragma unroll
            for (int pass = 0; pass < 2; ++pass)
                *(uint4*)&hsout[(size_t)(nbase + nd) * 64 + c0 + pass * 32] =
                    *(uint4*)&s_a[w][nd][c0 + pass * 32];
        } else {
            // proj: h3 = o @ w2 (64x3); per-lane partials over its 4 chs,
            // xor-shuffle reduce across the 16 lanes sharing a row-group
            float p[4][3];
#pragma unroll
            for (int j = 0; j < 4; ++j)
#pragma unroll
                for (int m = 0; m < 3; ++m) p[j][m] = 0.f;
            int myc = lane & 15;
#pragma unroll
            for (int ct = 0; ct < 4; ++ct) {
                int ch = ct * 16 + myc;
                float w0 = s_Wnf[ch * 3 + 0], w1 = s_Wnf[ch * 3 + 1], w2v = s_Wnf[ch * 3 + 2];
#pragma unroll
                for (int j = 0; j < 4; ++j) {
                    p[j][0] = fmaf(o[ct][j], w0, p[j][0]);
                    p[j][1] = fmaf(o[ct][j], w1, p[j][1]);
                    p[j][2] = fmaf(o[ct][j], w2v, p[j][2]);
                }
            }
#pragma unroll
            for (int mask = 1; mask <= 8; mask <<= 1)
#pragma unroll
                for (int j = 0; j < 4; ++j)
#pragma unroll
                    for (int m = 0; m < 3; ++m)
                        p[j][m] += __shfl_xor(p[j][m], mask, 64);
            if (myc == 0) {
#pragma unroll
                for (int j = 0; j < 4; ++j) {
                    int node = nbase + kg * 4 + j;
                    float dv = dinv[node];
                    hs3[node] = make_float4(dv * p[j][0], dv * p[j][1], dv * p[j][2], 0.f);
                }
            }
            __syncthreads();  // protect s_a before next tile's phase-1
        }
    }
}

// stage-2: aggregation (thread-per-node over CSR rowstart) + final y3 + BN stats.
__global__ void __launch_bounds__(256)
k_agg3(const float4* __restrict__ hs3, const int* __restrict__ cursor,
       const int* __restrict__ src4, const float* __restrict__ dinv,
       const float* __restrict__ b2, float4* __restrict__ y3,
       float* __restrict__ bnsum) {
    int v = blockIdx.x * blockDim.x + threadIdx.x;
    float y0 = 0.f, y1 = 0.f, y2 = 0.f;
    bool valid = v < N_NODES;
    if (valid) {
        int start = cursor[v];
        int end = (v + 1 < N_NODES) ? cursor[v + 1] : N_EDGES;
        float a0 = 0.f, a1 = 0.f, a2 = 0.f;
        int e = start;
        for (; e + 4 <= end; e += 4) {
            int c[4];
#pragma unroll
            for (int u = 0; u < 4; ++u) c[u] = src4[e + u];
#pragma unroll
            for (int u = 0; u < 4; ++u) {
                float4 h = hs3[c[u]];
                a0 += h.x; a1 += h.y; a2 += h.z;
            }
        }
        for (; e < end; ++e) {
            float4 h = hs3[src4[e]];
            a0 += h.x; a1 += h.y; a2 += h.z;
        }
        float dv = dinv[v];
        float4 hsv = hs3[v];
        y0 = dv * (a0 + 2.f * hsv.x) + b2[0];
        y1 = dv * (a1 + 2.f * hsv.y) + b2[1];
        y2 = dv * (a2 + 2.f * hsv.z) + b2[2];
        y3[v] = make_float4(y0, y1, y2, 0.f);
    }
    __shared__ float sm[256];
    float vals[6] = {y0, y1, y2, y0 * y0, y1 * y1, y2 * y2};
    for (int c = 0; c < 6; ++c) {
        sm[threadIdx.x] = valid ? vals[c] : 0.f;
        __syncthreads();
        for (int off = 128; off > 0; off >>= 1) {
            if (threadIdx.x < off) sm[threadIdx.x] += sm[threadIdx.x + off];
            __syncthreads();
        }
        if (threadIdx.x == 0) atomicAdd(&bnsum[c], sm[0]);
        __syncthreads();
    }
}

// final stage post: BN + pool(3,1) + leaky + 3x3 linear + leaky
__global__ void k_post3(const float4* __restrict__ y3, const float* __restrict__ bnsum,
                        const float* __restrict__ g, const float* __restrict__ bb,
                        const float* __restrict__ lw, const float* __restrict__ lb,
                        float* __restrict__ out) {
    int v = blockIdx.x * blockDim.x + threadIdx.x;
    if (v >= N_NODES) return;
    float inv_n = 1.0f / (float)N_NODES;
    float sc[3], sh[3];
#pragma unroll
    for (int c = 0; c < 3; ++c) {
        float mean = bnsum[c] * inv_n;
        float var = fmaxf(bnsum[3 + c] * inv_n - mean * mean, 0.f);
        sc[c] = g[c] * rsqrtf(var + 1e-5f);
        sh[c] = bb[c] - mean * sc[c];
    }
    float4 y = y3[v];
    float z0 = fmaf(y.x, sc[0], sh[0]);
    float z1 = fmaf(y.y, sc[1], sh[1]);
    float z2 = fmaf(y.z, sc[2], sh[2]);
    float p0 = fmaxf(z0, z1);
    float p1 = fmaxf(p0, z2);
    float p2 = fmaxf(z1, z2);
    float a0 = leaky(p0), a1 = leaky(p1), a2 = leaky(p2);
    float o0 = leaky(lb[0] + a0 * lw[0] + a1 * lw[1] + a2 * lw[2]);
    float o1 = leaky(lb[1] + a0 * lw[3] + a1 * lw[4] + a2 * lw[5]);
    float o2 = leaky(lb[2] + a0 * lw[6] + a1 * lw[7] + a2 * lw[8]);
    out[v * 3 + 0] = o0;
    out[v * 3 + 1] = o1;
    out[v * 3 + 2] = o2;
}

// ---------------- launcher ----------------

extern "C" void kernel_launch(void* const* d_in, const int* in_sizes, int n_in,
                              void* d_out, int out_size, void* d_ws, size_t ws_size,
                              hipStream_t stream) {
    const float* x  = (const float*)d_in[0];
    const int*   ei = (const int*)d_in[1];
    const float* w0 = (const float*)d_in[2];
    const float* b0 = (const float*)d_in[3];
    const float* g0 = (const float*)d_in[4];
    const float* bb0 = (const float*)d_in[5];
    const float* lw0 = (const float*)d_in[6];
    const float* lb0 = (const float*)d_in[7];
    const float* w1 = (const float*)d_in[8];
    const float* b1 = (const float*)d_in[9];
    const float* g1 = (const float*)d_in[10];
    const float* bb1 = (const float*)d_in[11];
    const float* lw1 = (const float*)d_in[12];
    const float* lb1 = (const float*)d_in[13];
    const float* w2 = (const float*)d_in[14];
    const float* b2 = (const float*)d_in[15];
    const float* g2 = (const float*)d_in[16];
    const float* bb2 = (const float*)d_in[17];
    const float* lw2 = (const float*)d_in[18];
    const float* lb2 = (const float*)d_in[19];
    float* out = (float*)d_out;

    // workspace layout (16B-aligned first) — byte-identical to the 416us baseline
    char* w = (char*)d_ws;
    float* yagg = (float*)w;       w += (size_t)N_NODES * 64 * 4;        // 20.48 MB (pre-BN y)
    int* src4 = (int*)w;           w += (size_t)N_EDGES * 8;             // first 5.12MB of ex-ed2 slot
    unsigned int* fpairs = (unsigned int*)w; w += (size_t)NFB * FB_CAP * 4;  // 6.4 MB
    bf16* hs = (bf16*)w;           w += (size_t)N_NODES * 64 * 2;        // 10.24 MB
    float4* hs3 = (float4*)w;      w += (size_t)N_NODES * 16;            // 1.28 MB
    float4* y3 = (float4*)w;       w += (size_t)N_NODES * 16;            // 1.28 MB
    int* fbase = (int*)w;          w += (size_t)N_NODES * 4;             // (slot kept; bnrep lives here)
    float* dinv = (float*)w;       w += (size_t)N_NODES * 4;
    int* cursor = (int*)w;         w += (size_t)N_NODES * 4;
    int* partial = (int*)w;        w += 512 * 4;                         // unused (layout kept)
    float* bnsum = (float*)w;      w += 384 * 4;
    int* ctails = (int*)w;         w += NCB * 4;
    int* ftails = (int*)w;         w += NFB * 4;
    (void)partial;
    // cpairs overlays yagg (dead after k_refine, before k_aggc writes y) — 5.25 MB
    unsigned int* cpairs = (unsigned int*)yagg;
    // pkw overlays y3 (pkw last read in stage-1 k_post64; y3 first written by k_agg3)
    uint4* pkw = (uint4*)y3;
    // BN-stat replicas carved from the fbase slot (+16 KB)
    float* bnrep = (float*)((char*)fbase + 16384);  // 2 stages x 8 reps x 128 = 8 KB

    const int NB = (N_NODES + 255) / 256;  // 313

    // --- graph/CSR setup: coarse bin -> refine -> LDS sort+h0 (self-based) ---
    k_init<<<8, 256, 0, stream>>>(bnsum, bnrep, ctails, ftails, lw0, w1, lw1, pkw);
    k_part<<<N_EDGES / EPB, 256, 0, stream>>>(ei, cpairs, ctails);
    k_refine<<<64 * 16, 256, 0, stream>>>(cpairs, ctails, ftails, fpairs);
    k_sortfine<<<NFB, 256, 0, stream>>>(fpairs, ftails, src4, dinv, cursor,
                                        x, w0, hs);

    // --- stage 0 ---
    k_aggc<<<1250, 512, 0, stream>>>(hs, src4, cursor, dinv, b0, yagg, bnrep);
    k_post64<1, 0><<<1250, 256, 0, stream>>>(yagg, dinv, bnrep, g0, bb0,
                                             pkw, lb0, pkw + 512, nullptr,
                                             hs, nullptr);

    // --- stage 1 ---
    k_aggc<<<1250, 512, 0, stream>>>(hs, src4, cursor, dinv, b1, yagg, bnrep + 1024);
    k_post64<2, 1><<<1250, 256, 0, stream>>>(yagg, dinv, bnrep + 1024, g1, bb1,
                                             pkw + 1024, lb1, nullptr, w2,
                                             nullptr, hs3);

    // --- stage 2 (C=3): agg + BN stats fused ---
    k_agg3<<<NB, 256, 0, stream>>>(hs3, cursor, src4, dinv, b2, y3, bnsum + 256);
    k_post3<<<NB, 256, 0, stream>>>(y3, bnsum + 256, g2, bb2, lw2, lb2, out);
}